// Round 4
// baseline (196.499 us; speedup 1.0000x reference)
//
#include <hip/hip_runtime.h>
#include <math.h>

#define NP 50000
#define CH 64
#define KMAX 64
#define KNN 16
#define NB 25
#define PTS (NP / NB)            // 2000
#define EPSF 1e-16f
#define NTILES (NP / 16)         // 3125 (16-node tiles for qkv)
#define ATILES (NP / 4)          // 12500 (4-node tiles for attn)
#define L2E 1.4426950408889634f
#define LN2 0.6931471805599453f
#define PPB 8                    // pool partials per cloud
#define PROWS (PTS / PPB)        // 250

typedef __attribute__((ext_vector_type(8))) short short8;
typedef __attribute__((ext_vector_type(4))) float float4v;
typedef __attribute__((ext_vector_type(4))) unsigned int uint4v;
typedef __attribute__((ext_vector_type(2))) unsigned int uint2v;
typedef __attribute__((ext_vector_type(4))) unsigned short ushort4v;

__device__ __forceinline__ ushort f2b(float f) {
  unsigned u = __float_as_uint(f);
  unsigned r = (u + 0x7FFFu + ((u >> 16) & 1u)) >> 16;
  return (ushort)r;
}
__device__ __forceinline__ float b2f(ushort h) {
  return __uint_as_float(((unsigned)h) << 16);
}

// ws layout (bytes):
//   qbf  : 3 * NP * CH * 2   (bf16, log2e-scaled Q)
//   kvp  : 3 * NP * CH * 4   (packed dword: K_s bf16 hi | V bf16 lo)
//   wpack: 36864 ushort (A-frag layout; Q,K pre-scaled by log2e)
//   poolP: NB * PPB * CH fp32 (per-cloud pool partials)
#define QBF_BYTES   ((size_t)3 * NP * CH * 2)
#define KVP_BYTES   ((size_t)3 * NP * CH * 4)
#define WPACK_ELEMS (9 * 4 * 2 * 64 * 8)

// ---------------------------------------------------------------------------
// Kernel 0: prep = pool partials (blocks 0..NB*PPB-1) + W pack.
// ---------------------------------------------------------------------------
__global__ __launch_bounds__(256) void prep_kernel(
    const float* __restrict__ x,
    const float* __restrict__ Wv,
    const float* __restrict__ Wq,
    const float* __restrict__ Wk,
    ushort* __restrict__ wpack,
    float* __restrict__ poolP) {
  const int tid = threadIdx.x;
  const int bid = blockIdx.x;
  __shared__ float red[4][CH];

  if (bid < NB * PPB) {                 // ---- pool partial path ----
    const int lane = tid & 63;
    const int wave = tid >> 6;
    const int cloud = bid >> 3;
    const int part  = bid & 7;
    const float* xb = x + ((size_t)cloud * PTS + part * PROWS) * CH;
    float m0 = -INFINITY, m1 = -INFINITY;
    for (int r = wave * 2; r < PROWS; r += 8) {
      m0 = fmaxf(m0, xb[(size_t)(r + 0) * CH + lane]);
      m1 = fmaxf(m1, xb[(size_t)(r + 1) * CH + lane]);
    }
    red[wave][lane] = fmaxf(m0, m1);
    __syncthreads();
    if (wave == 0) {
      poolP[(size_t)bid * CH + lane] = fmaxf(fmaxf(red[0][lane], red[1][lane]),
                                             fmaxf(red[2][lane], red[3][lane]));
    }
  } else {                              // ---- W pack path ----
    int pid = (bid - NB * PPB) * 256 + tid;
    if (pid < WPACK_ELEMS) {
      int j     = pid & 7;
      int lane  = (pid >> 3) & 63;
      int kstep = (pid >> 9) & 1;
      int mtile = (pid >> 10) & 3;
      int mat   = pid >> 12;
      const float* W;
      int d;
      float scale;
      if (mat < 3)      { W = Wq; d = mat;     scale = L2E; }
      else if (mat < 6) { W = Wk; d = mat - 3; scale = L2E; }
      else              { W = Wv; d = mat - 6; scale = 1.f; }
      int oc = mtile * 16 + (lane & 15);
      int ic = kstep * 32 + ((lane >> 4) & 3) * 8 + j;
      wpack[pid] = f2b(W[d * CH * CH + ic * CH + oc] * scale);
    }
  }
}

// ---------------------------------------------------------------------------
// Kernel 1: projections via MFMA 16x16x32 bf16. One block per 16-node tile,
// 6 waves = 6 slices. x staged once (f32 -> bf16) into XOR-swizzled LDS.
// NEW: XCD swizzle matching attn's node->XCD map, so the kvp/qbf rows this
// XCD writes are the rows its attn blocks later gather (L2 affinity).
// ---------------------------------------------------------------------------
__global__ __launch_bounds__(384) void qkv_mfma(
    const float* __restrict__ x,
    const ushort* __restrict__ wpack,
    ushort* __restrict__ qbf,
    unsigned int* __restrict__ kvp) {
  const int bx  = blockIdx.x;
  const int xcd = bx & 7;
  const int kk  = bx >> 3;
  const int tbase = (NTILES * xcd) >> 3;
  const int tcnt  = ((NTILES * (xcd + 1)) >> 3) - tbase;
  if (kk >= tcnt) return;
  const int tile = tbase + kk;

  const int lane = threadIdx.x;
  const int wy   = threadIdx.y;
  const int tid  = wy * 64 + lane;

  __shared__ ushort xs[16 * 64];            // 2 KB, XOR-swizzled rows

  if (tid < 256) {                          // stage: 16 nodes x 16 chunks(4ch)
    int node  = tid >> 4;
    int chunk = tid & 15;
    float4v v = *(const float4v*)(x + ((size_t)(tile * 16 + node)) * CH + chunk * 4);
    ushort4v o;
    o[0] = f2b(v[0]); o[1] = f2b(v[1]); o[2] = f2b(v[2]); o[3] = f2b(v[3]);
    int byte = (chunk * 8) ^ ((node & 7) << 4);
    *(ushort4v*)((char*)xs + node * 128 + byte) = o;
  }
  __syncthreads();

  const int node = lane & 15;
  const int kb2  = (lane >> 4) * 16;        // byte offset of this group's k-slice
  const char* xrow = (const char*)xs + node * 128;
  const int sw = (node & 7) << 4;
  short8 b0 = *(const short8*)(xrow + (kb2 ^ sw));
  short8 b1 = *(const short8*)(xrow + ((kb2 + 64) ^ sw));
  const int myNode = tile * 16 + node;

  if (wy < 3) {                             // ---- Q slice ----
    const int dd = wy;
    ushort* outQ = qbf + (size_t)dd * NP * CH;
#pragma unroll
    for (int mt = 0; mt < 4; ++mt) {
      short8 a0 = *(const short8*)(wpack +
          ((((size_t)dd * 4 + mt) * 2 + 0) * 64 + lane) * 8);
      short8 a1 = *(const short8*)(wpack +
          ((((size_t)dd * 4 + mt) * 2 + 1) * 64 + lane) * 8);
      float4v acc = {0.f, 0.f, 0.f, 0.f};
      acc = __builtin_amdgcn_mfma_f32_16x16x32_bf16(a0, b0, acc, 0, 0, 0);
      acc = __builtin_amdgcn_mfma_f32_16x16x32_bf16(a1, b1, acc, 0, 0, 0);
      int oc = mt * 16 + (lane >> 4) * 4;
      uint2v o;
      o[0] = (unsigned)f2b(acc[0]) | ((unsigned)f2b(acc[1]) << 16);
      o[1] = (unsigned)f2b(acc[2]) | ((unsigned)f2b(acc[3]) << 16);
      *(uint2v*)(outQ + (size_t)myNode * CH + oc) = o;
    }
  } else {                                  // ---- KV packed slice ----
    const int dd = wy - 3;
    unsigned int* outKV = kvp + (size_t)dd * NP * CH;
#pragma unroll
    for (int mt = 0; mt < 4; ++mt) {
      short8 k0 = *(const short8*)(wpack +
          ((((size_t)(3 + dd) * 4 + mt) * 2 + 0) * 64 + lane) * 8);
      short8 k1 = *(const short8*)(wpack +
          ((((size_t)(3 + dd) * 4 + mt) * 2 + 1) * 64 + lane) * 8);
      short8 v0 = *(const short8*)(wpack +
          ((((size_t)(6 + dd) * 4 + mt) * 2 + 0) * 64 + lane) * 8);
      short8 v1 = *(const short8*)(wpack +
          ((((size_t)(6 + dd) * 4 + mt) * 2 + 1) * 64 + lane) * 8);
      float4v aK = {0.f, 0.f, 0.f, 0.f};
      float4v aV = {0.f, 0.f, 0.f, 0.f};
      aK = __builtin_amdgcn_mfma_f32_16x16x32_bf16(k0, b0, aK, 0, 0, 0);
      aK = __builtin_amdgcn_mfma_f32_16x16x32_bf16(k1, b1, aK, 0, 0, 0);
      aV = __builtin_amdgcn_mfma_f32_16x16x32_bf16(v0, b0, aV, 0, 0, 0);
      aV = __builtin_amdgcn_mfma_f32_16x16x32_bf16(v1, b1, aV, 0, 0, 0);
      int oc = mt * 16 + (lane >> 4) * 4;
      uint4v o;
#pragma unroll
      for (int i = 0; i < 4; ++i)
        o[i] = ((unsigned)f2b(aK[i]) << 16) | (unsigned)f2b(aV[i]);
      *(uint4v*)(outKV + (size_t)myNode * CH + oc) = o;
    }
  }
}

// ---------------------------------------------------------------------------
// Kernel 2: fused attention v5 = round-0 proven geometry + surgical stage
// fixes ONLY (inner 8-edge body verbatim):
//   - stage 48 compacted per-wave-contiguous slots/node instead of all 64
//     (25% fewer gathers; waves 0-3, lanes 0-47, one gather per lane);
//     slot s: wv=s>>3, e=s&7, dds=wv%3, p=(wv>=3?8<<dds:0)+(e<<dds)
//   - per-wave setup loads (q, Wp, bp) + combine-wave pool/x preload issued
//     BEFORE the stage barrier so they fly under the stage gathers
//   - combine on wave 5 (non-staging) with preloaded epilogue operands
//   - inner walk: constant 16B stride -> immediate-offset ds_reads
// ---------------------------------------------------------------------------
__global__ __launch_bounds__(384, 6) void attn_kernel(
    const float* __restrict__ x,
    const float* __restrict__ pos,
    const float* __restrict__ Wp,
    const float* __restrict__ bp,
    const int*   __restrict__ edge_src,
    const ushort* __restrict__ qbf,
    const unsigned int* __restrict__ kvp,
    const float* __restrict__ poolP,
    float* __restrict__ out) {
  const int bx  = blockIdx.x;
  const int xcd = bx & 7;
  const int kk  = bx >> 3;
  const int base = (ATILES * xcd) >> 3;
  const int cnt  = ((ATILES * (xcd + 1)) >> 3) - base;
  if (kk >= cnt) return;                    // whole-block uniform
  const int node0 = (base + kk) * 4;

  const int wy   = threadIdx.y;             // 0..5
  const int dd   = wy % 3;                  // wave-uniform dilation
  const int lane = threadIdx.x;
  const int g    = lane >> 4;
  const int cl   = lane & 15;
  const int node = node0 + g;

  __shared__ float sEdge[4 * 196];          // [nl][slot*4] {relx,rely,relz,rowOfs}
  __shared__ float sS[6 * 4 * 68];          // [wy][nl][ch] partial s
  __shared__ float sP[6 * 4 * 68];          // [wy][nl][ch] partial accv-q*s

  // ---- setup loads (all waves) — issued before stage so they overlap ----
  const unsigned clOfs = (unsigned)(cl << 4);
  float4v bq, qorig, wp0, wp1, wp2;
  {
    ushort4v qh = *(const ushort4v*)(qbf + ((size_t)dd * NP + node) * CH + cl * 4);
    const float* WpD = Wp + dd * 192;
    wp0 = *(const float4v*)(WpD + 0 * 64 + cl * 4) * L2E;
    wp1 = *(const float4v*)(WpD + 1 * 64 + cl * 4) * L2E;
    wp2 = *(const float4v*)(WpD + 2 * 64 + cl * 4) * L2E;
    float4v bpv = *(const float4v*)(bp + dd * 64 + cl * 4);
    float4v qf;
#pragma unroll
    for (int i = 0; i < 4; ++i) qf[i] = b2f(qh[i]);
    bq = qf + bpv * L2E;
    qorig = qf * LN2;
  }

  // ---- epilogue preload (combine wave only) — also before the barrier ----
  float4v pvmax = {0.f, 0.f, 0.f, 0.f};
  float4v xres  = {0.f, 0.f, 0.f, 0.f};
  if (wy == 5) {
    const int b = node0 / PTS;              // 4-node tile never straddles cloud
    const float* pp = poolP + (size_t)(b * PPB) * CH + cl * 4;
    pvmax = *(const float4v*)pp;
#pragma unroll
    for (int q2 = 1; q2 < PPB; ++q2) {
      float4v t2 = *(const float4v*)(pp + (size_t)q2 * CH);
#pragma unroll
      for (int i = 0; i < 4; ++i) pvmax[i] = fmaxf(pvmax[i], t2[i]);
    }
    xres = *(const float4v*)(x + (size_t)node * CH + cl * 4);
  }

  // ---- stage: wave w owns node w; lanes 0-47 one compacted slot each ----
  if (wy < 4 && lane < 48) {
    int wv = lane >> 3, e = lane & 7;
    int dds = wv >= 3 ? wv - 3 : wv;
    int p = (wv >= 3 ? (8 << dds) : 0) + (e << dds);
    int nd = node0 + wy;
    int j = edge_src[(size_t)nd * KMAX + p];
    float4v w;
    w[0] = pos[nd * 3 + 0] - pos[j * 3 + 0];
    w[1] = pos[nd * 3 + 1] - pos[j * 3 + 1];
    w[2] = pos[nd * 3 + 2] - pos[j * 3 + 2];
    w[3] = __int_as_float(j << 8);          // byte offset of packed-KV row
    *(float4v*)&sEdge[wy * 196 + lane * 4] = w;
  }
  __syncthreads();

  const char* KVb = (const char*)(kvp + (size_t)dd * NP * CH);
  // wave wy's 8 slots are contiguous at [g][wy*8 .. wy*8+7]
  const float* ep = &sEdge[g * 196 + wy * 32];

  float4v s    = {0.f, 0.f, 0.f, 0.f};
  float4v accv = {0.f, 0.f, 0.f, 0.f};
#pragma unroll
  for (int e = 0; e < 8; ++e) {
    float4v w = *(const float4v*)(ep + e * 4);
    uint4v u = *(const uint4v*)(KVb + (__float_as_uint(w[3]) + clOfs));
    float4v kf, vf, wgt;
#pragma unroll
    for (int i = 0; i < 4; ++i) kf[i] = __uint_as_float(u[i] & 0xFFFF0000u);
#pragma unroll
    for (int i = 0; i < 4; ++i) vf[i] = __uint_as_float(u[i] << 16);
    float4v t = bq + w[0] * wp0 + w[1] * wp1 + w[2] * wp2;  // q_s + delta_s
    float4v a = t - kf;
#pragma unroll
    for (int i = 0; i < 4; ++i) wgt[i] = __builtin_amdgcn_exp2f(a[i]);
    s += wgt;
    accv += wgt * (vf + t * LN2);           // w * (v + ln2*t)
  }

  // publish partials: P = accv - q*s  (q uniform across halves)
  float4v P = accv - qorig * s;
  *(float4v*)&sS[(wy * 4 + g) * 68 + cl * 4] = s;
  *(float4v*)&sP[(wy * 4 + g) * 68 + cl * 4] = P;
  __syncthreads();

  if (wy == 5) {                            // combine wave (preloaded pool/x)
    float4v res;
#pragma unroll
    for (int d2 = 0; d2 < 3; ++d2) {
      float4v s0 = *(const float4v*)&sS[((d2    ) * 4 + g) * 68 + cl * 4];
      float4v s1 = *(const float4v*)&sS[((d2 + 3) * 4 + g) * 68 + cl * 4];
      float4v p0 = *(const float4v*)&sP[((d2    ) * 4 + g) * 68 + cl * 4];
      float4v p1 = *(const float4v*)&sP[((d2 + 3) * 4 + g) * 68 + cl * 4];
      float4v st = s0 + s1;
      float4v pt = p0 + p1;
      float4v r;
#pragma unroll
      for (int i = 0; i < 4; ++i)
        r[i] = pt[i] * __builtin_amdgcn_rcpf(st[i] + EPSF);
      if (d2 == 0) res = r;
      else {
#pragma unroll
        for (int i = 0; i < 4; ++i) res[i] = fmaxf(res[i], r[i]);
      }
    }
#pragma unroll
    for (int i = 0; i < 4; ++i) res[i] = fmaxf(res[i], pvmax[i]) + xres[i];
    *(float4v*)(out + (size_t)node * CH + cl * 4) = res;
  }
}

// ---------------------------------------------------------------------------
extern "C" void kernel_launch(void* const* d_in, const int* in_sizes, int n_in,
                              void* d_out, int out_size, void* d_ws, size_t ws_size,
                              hipStream_t stream) {
  const float* x    = (const float*)d_in[0];
  const float* pos  = (const float*)d_in[1];
  const float* Wv   = (const float*)d_in[2];
  const float* Wq   = (const float*)d_in[3];
  const float* Wk   = (const float*)d_in[4];
  const float* Wp   = (const float*)d_in[5];
  const float* bp   = (const float*)d_in[6];
  const int*   ei   = (const int*)d_in[7];
  float* out = (float*)d_out;

  char* wsb = (char*)d_ws;
  ushort* qbf   = (ushort*)wsb;
  unsigned int* kvp = (unsigned int*)(wsb + QBF_BYTES);
  ushort* wpack = (ushort*)(wsb + QBF_BYTES + KVP_BYTES);
  float*  poolP = (float*)(wsb + QBF_BYTES + KVP_BYTES +
                           (size_t)WPACK_ELEMS * 2);

  // 0) pool partials + W pack
  {
    int packBlocks = (WPACK_ELEMS + 255) / 256;
    dim3 grid(NB * PPB + packBlocks);
    hipLaunchKernelGGL(prep_kernel, grid, dim3(256), 0, stream,
                       x, Wv, Wq, Wk, wpack, poolP);
  }
  // 1) Q + packed KV via MFMA (XCD-swizzled to match attn's node map)
  {
    dim3 grid(8 * ((NTILES + 7) / 8));
    dim3 block(64, 6);
    hipLaunchKernelGGL(qkv_mfma, grid, block, 0, stream, x, wpack, qbf, kvp);
  }
  // 2) fused attention + combine
  {
    dim3 grid(8 * ((ATILES + 7) / 8));
    dim3 block(64, 6);
    hipLaunchKernelGGL(attn_kernel, grid, block, 0, stream,
                       x, pos, Wp, bp, ei, qbf, kvp, poolP, out);
  }
}

// Round 5
// 188.382 us; speedup vs baseline: 1.0431x; 1.0431x over previous
//
#include <hip/hip_runtime.h>
#include <math.h>

#define NP 50000
#define CH 64
#define KMAX 64
#define KNN 16
#define NB 25
#define PTS (NP / NB)            // 2000
#define EPSF 1e-16f
#define NTILES (NP / 16)         // 3125 (16-node tiles for qkv)
#define ATILES (NP / 4)          // 12500 (4-node tiles for attn)
#define L2E 1.4426950408889634f
#define LN2 0.6931471805599453f
#define PPB 8                    // pool partials per cloud
#define PROWS (PTS / PPB)        // 250
#define POOLBLKS (NB * PPB)      // 200

typedef __attribute__((ext_vector_type(8))) short short8;
typedef __attribute__((ext_vector_type(4))) float float4v;
typedef __attribute__((ext_vector_type(4))) unsigned int uint4v;
typedef __attribute__((ext_vector_type(2))) unsigned int uint2v;
typedef __attribute__((ext_vector_type(4))) unsigned short ushort4v;

__device__ __forceinline__ ushort f2b(float f) {
  unsigned u = __float_as_uint(f);
  unsigned r = (u + 0x7FFFu + ((u >> 16) & 1u)) >> 16;
  return (ushort)r;
}
__device__ __forceinline__ float b2f(ushort h) {
  return __uint_as_float(((unsigned)h) << 16);
}

// ws layout (bytes):
//   qbf  : 3 * NP * CH * 2   (bf16, log2e-scaled Q)
//   kvp  : 3 * NP * CH * 4   (packed dword: K_s bf16 hi | V bf16 lo)
//   poolP: NB * PPB * CH fp32 (per-cloud pool partials)
#define QBF_BYTES   ((size_t)3 * NP * CH * 2)
#define KVP_BYTES   ((size_t)3 * NP * CH * 4)

// ---------------------------------------------------------------------------
// Kernel A: FUSED pool partials + QKV projections (2 dispatches total now).
// Blocks 0..POOLBLKS-1: per-cloud-slice max partials (6 waves).
// Blocks POOLBLKS.. : one 16-node tile each, 6 waves = 6 slices
//   (wy 0..2 = Q_dd, wy 3..5 = KV_dd packed). Each wave builds its own W
//   A-fragments DIRECTLY from the f32 weights (L2-hot strided loads),
//   eliminating the wpack intermediate and the prep->qkv dependency.
//   x staged once f32->bf16 into XOR-swizzled LDS.
// A-frag mapping (verified vs old wpack semantics):
//   frag[mt][ks][j] = f2b(W[d][ks*32 + (lane>>4)*8 + j][mt*16 + (lane&15)]*s)
// ---------------------------------------------------------------------------
__global__ __launch_bounds__(384) void fused_pool_qkv(
    const float* __restrict__ x,
    const float* __restrict__ Wv,
    const float* __restrict__ Wq,
    const float* __restrict__ Wk,
    ushort* __restrict__ qbf,
    unsigned int* __restrict__ kvp,
    float* __restrict__ poolP) {
  const int bid  = blockIdx.x;
  const int lane = threadIdx.x;
  const int wy   = threadIdx.y;
  const int tid  = wy * 64 + lane;

  __shared__ float  red[6][CH];             // pool path
  __shared__ ushort xs[16 * 64];            // qkv path, XOR-swizzled rows

  if (bid < POOLBLKS) {                     // ---- pool partial path ----
    const int cloud = bid >> 3;
    const int part  = bid & 7;
    const float* xb = x + ((size_t)cloud * PTS + part * PROWS) * CH;
    float m = -INFINITY;
    for (int r = wy; r < PROWS; r += 6)
      m = fmaxf(m, xb[(size_t)r * CH + lane]);
    red[wy][lane] = m;
    __syncthreads();
    if (wy == 0) {
      float mm = red[0][lane];
#pragma unroll
      for (int w2 = 1; w2 < 6; ++w2) mm = fmaxf(mm, red[w2][lane]);
      poolP[(size_t)bid * CH + lane] = mm;
    }
    return;
  }

  // ---- qkv tile path ----
  const int tile = bid - POOLBLKS;

  if (tid < 256) {                          // stage: 16 nodes x 16 chunks(4ch)
    int node  = tid >> 4;
    int chunk = tid & 15;
    float4v v = *(const float4v*)(x + ((size_t)(tile * 16 + node)) * CH + chunk * 4);
    ushort4v o;
    o[0] = f2b(v[0]); o[1] = f2b(v[1]); o[2] = f2b(v[2]); o[3] = f2b(v[3]);
    int byte = (chunk * 8) ^ ((node & 7) << 4);
    *(ushort4v*)((char*)xs + node * 128 + byte) = o;
  }

  // W fragment construction (global f32, L2-hot after first blocks) —
  // issued before the barrier so it overlaps the x staging.
  const int ocl = lane & 15;
  const int icl = (lane >> 4) * 8;
  const int dd  = wy < 3 ? wy : wy - 3;

  short8 fA[4][2], fB[4][2];                // Q: fA only. KV: fA=K, fB=V.
  if (wy < 3) {
    const float* Wb = Wq + (size_t)dd * CH * CH + ocl;
#pragma unroll
    for (int mt = 0; mt < 4; ++mt)
#pragma unroll
      for (int ks = 0; ks < 2; ++ks) {
        short8 a;
#pragma unroll
        for (int j = 0; j < 8; ++j)
          a[j] = (short)f2b(Wb[(size_t)(ks * 32 + icl + j) * CH + mt * 16] * L2E);
        fA[mt][ks] = a;
      }
  } else {
    const float* Wkb = Wk + (size_t)dd * CH * CH + ocl;
    const float* Wvb = Wv + (size_t)dd * CH * CH + ocl;
#pragma unroll
    for (int mt = 0; mt < 4; ++mt)
#pragma unroll
      for (int ks = 0; ks < 2; ++ks) {
        short8 a, b;
#pragma unroll
        for (int j = 0; j < 8; ++j) {
          a[j] = (short)f2b(Wkb[(size_t)(ks * 32 + icl + j) * CH + mt * 16] * L2E);
          b[j] = (short)f2b(Wvb[(size_t)(ks * 32 + icl + j) * CH + mt * 16]);
        }
        fA[mt][ks] = a;
        fB[mt][ks] = b;
      }
  }
  __syncthreads();

  const int node = lane & 15;
  const int kb2  = (lane >> 4) * 16;        // byte offset of this group's k-slice
  const char* xrow = (const char*)xs + node * 128;
  const int sw = (node & 7) << 4;
  short8 b0 = *(const short8*)(xrow + (kb2 ^ sw));
  short8 b1 = *(const short8*)(xrow + ((kb2 + 64) ^ sw));
  const int myNode = tile * 16 + node;

  if (wy < 3) {                             // ---- Q slice ----
    ushort* outQ = qbf + (size_t)dd * NP * CH;
#pragma unroll
    for (int mt = 0; mt < 4; ++mt) {
      float4v acc = {0.f, 0.f, 0.f, 0.f};
      acc = __builtin_amdgcn_mfma_f32_16x16x32_bf16(fA[mt][0], b0, acc, 0, 0, 0);
      acc = __builtin_amdgcn_mfma_f32_16x16x32_bf16(fA[mt][1], b1, acc, 0, 0, 0);
      int oc = mt * 16 + (lane >> 4) * 4;
      uint2v o;
      o[0] = (unsigned)f2b(acc[0]) | ((unsigned)f2b(acc[1]) << 16);
      o[1] = (unsigned)f2b(acc[2]) | ((unsigned)f2b(acc[3]) << 16);
      *(uint2v*)(outQ + (size_t)myNode * CH + oc) = o;
    }
  } else {                                  // ---- KV packed slice ----
    unsigned int* outKV = kvp + (size_t)dd * NP * CH;
#pragma unroll
    for (int mt = 0; mt < 4; ++mt) {
      float4v aK = {0.f, 0.f, 0.f, 0.f};
      float4v aV = {0.f, 0.f, 0.f, 0.f};
      aK = __builtin_amdgcn_mfma_f32_16x16x32_bf16(fA[mt][0], b0, aK, 0, 0, 0);
      aK = __builtin_amdgcn_mfma_f32_16x16x32_bf16(fA[mt][1], b1, aK, 0, 0, 0);
      aV = __builtin_amdgcn_mfma_f32_16x16x32_bf16(fB[mt][0], b0, aV, 0, 0, 0);
      aV = __builtin_amdgcn_mfma_f32_16x16x32_bf16(fB[mt][1], b1, aV, 0, 0, 0);
      int oc = mt * 16 + (lane >> 4) * 4;
      uint4v o;
#pragma unroll
      for (int i = 0; i < 4; ++i)
        o[i] = ((unsigned)f2b(aK[i]) << 16) | (unsigned)f2b(aV[i]);
      *(uint4v*)(outKV + (size_t)myNode * CH + oc) = o;
    }
  }
}

// ---------------------------------------------------------------------------
// Kernel 2: fused attention — EXACT round-0 proven version (79.9 us).
// Block = (64,6): 4 nodes; wave wy = (dd, half), each handling 8 of a
// dilation's 16 edges. Partials published as {s, P = accv - q*s} -> single
// combine wave, only TWO barriers total. XCD swizzle keeps each XCD's
// gathers in ~3 clouds (L2-resident KV).  DO NOT MODIFY — every deviation
// tried in rounds 1/2/4 regressed (94/92/86 us vs 79.9).
// ---------------------------------------------------------------------------
__global__ __launch_bounds__(384, 6) void attn_kernel(
    const float* __restrict__ x,
    const float* __restrict__ pos,
    const float* __restrict__ Wp,
    const float* __restrict__ bp,
    const int*   __restrict__ edge_src,
    const ushort* __restrict__ qbf,
    const unsigned int* __restrict__ kvp,
    const float* __restrict__ poolP,
    float* __restrict__ out) {
  const int bx  = blockIdx.x;
  const int xcd = bx & 7;
  const int kk  = bx >> 3;
  const int base = (ATILES * xcd) >> 3;
  const int cnt  = ((ATILES * (xcd + 1)) >> 3) - base;
  if (kk >= cnt) return;                    // whole-block uniform
  const int node0 = (base + kk) * 4;

  const int wy   = threadIdx.y;             // 0..5
  const int dd   = wy % 3;                  // wave-uniform dilation
  const int half = wy / 3;                  // 0 or 1 (edge half)
  const int tid  = wy * 64 + threadIdx.x;

  __shared__ float sEdge[4 * 260];          // [nl][p] {relx,rely,relz,rowOfs}
  __shared__ float sS[6 * 4 * 68];          // [wy][nl][ch] partial s
  __shared__ float sP[6 * 4 * 68];          // [wy][nl][ch] partial accv-q*s

  if (tid < 256) {
    int nl = tid >> 6, p = tid & 63;
    int nd = node0 + nl;
    int j = edge_src[(size_t)nd * KMAX + p];
    float4v w;
    w[0] = pos[nd * 3 + 0] - pos[j * 3 + 0];
    w[1] = pos[nd * 3 + 1] - pos[j * 3 + 1];
    w[2] = pos[nd * 3 + 2] - pos[j * 3 + 2];
    w[3] = __int_as_float(j << 8);          // byte offset of packed-KV row
    *(float4v*)&sEdge[nl * 260 + p * 4] = w;
  }
  __syncthreads();

  const int lane = threadIdx.x;
  const int g    = lane >> 4;
  const int cl   = lane & 15;
  const int node = node0 + g;
  const unsigned clOfs = (unsigned)(cl << 4);

  float4v bq, qorig, wp0, wp1, wp2;
  {
    ushort4v qh = *(const ushort4v*)(qbf + ((size_t)dd * NP + node) * CH + cl * 4);
    const float* WpD = Wp + dd * 192;
    wp0 = *(const float4v*)(WpD + 0 * 64 + cl * 4) * L2E;
    wp1 = *(const float4v*)(WpD + 1 * 64 + cl * 4) * L2E;
    wp2 = *(const float4v*)(WpD + 2 * 64 + cl * 4) * L2E;
    float4v bpv = *(const float4v*)(bp + dd * 64 + cl * 4);
    float4v qf;
#pragma unroll
    for (int i = 0; i < 4; ++i) qf[i] = b2f(qh[i]);
    bq = qf + bpv * L2E;
    qorig = qf * LN2;
  }
  const char* KVb = (const char*)(kvp + (size_t)dd * NP * CH);

  // strength-reduced LDS walk: start at edge (half*8)<<dd, step (1<<dd)
  const float* ep = &sEdge[g * 260] + (((half * 8) << dd) * 4);
  const int estep = (1 << dd) * 4;          // floats per edge step

  float4v s    = {0.f, 0.f, 0.f, 0.f};
  float4v accv = {0.f, 0.f, 0.f, 0.f};
#pragma unroll
  for (int e = 0; e < 8; ++e) {
    float4v w = *(const float4v*)ep;
    ep += estep;
    uint4v u = *(const uint4v*)(KVb + (__float_as_uint(w[3]) + clOfs));
    float4v kf, vf, wgt;
#pragma unroll
    for (int i = 0; i < 4; ++i) kf[i] = __uint_as_float(u[i] & 0xFFFF0000u);
#pragma unroll
    for (int i = 0; i < 4; ++i) vf[i] = __uint_as_float(u[i] << 16);
    float4v t = bq + w[0] * wp0 + w[1] * wp1 + w[2] * wp2;  // q_s + delta_s
    float4v a = t - kf;
#pragma unroll
    for (int i = 0; i < 4; ++i) wgt[i] = __builtin_amdgcn_exp2f(a[i]);
    s += wgt;
    accv += wgt * (vf + t * LN2);           // w * (v + ln2*t)
  }

  // publish partials: P = accv - q*s  (q uniform across halves)
  float4v P = accv - qorig * s;
  *(float4v*)&sS[(wy * 4 + g) * 68 + cl * 4] = s;
  *(float4v*)&sP[(wy * 4 + g) * 68 + cl * 4] = P;
  __syncthreads();

  if (wy == 0) {                            // single combine wave
    float4v res;
#pragma unroll
    for (int d2 = 0; d2 < 3; ++d2) {
      float4v s0 = *(const float4v*)&sS[((d2    ) * 4 + g) * 68 + cl * 4];
      float4v s1 = *(const float4v*)&sS[((d2 + 3) * 4 + g) * 68 + cl * 4];
      float4v p0 = *(const float4v*)&sP[((d2    ) * 4 + g) * 68 + cl * 4];
      float4v p1 = *(const float4v*)&sP[((d2 + 3) * 4 + g) * 68 + cl * 4];
      float4v st = s0 + s1;
      float4v pt = p0 + p1;
      float4v r;
#pragma unroll
      for (int i = 0; i < 4; ++i)
        r[i] = pt[i] * __builtin_amdgcn_rcpf(st[i] + EPSF);
      if (d2 == 0) res = r;
      else {
#pragma unroll
        for (int i = 0; i < 4; ++i) res[i] = fmaxf(res[i], r[i]);
      }
    }
    const int b = node / PTS;
    const float* pp = poolP + (size_t)(b * PPB) * CH + cl * 4;
    float4v pv = *(const float4v*)pp;
#pragma unroll
    for (int q2 = 1; q2 < PPB; ++q2) {
      float4v t2 = *(const float4v*)(pp + (size_t)q2 * CH);
#pragma unroll
      for (int i = 0; i < 4; ++i) pv[i] = fmaxf(pv[i], t2[i]);
    }
    float4v xv = *(const float4v*)(x + (size_t)node * CH + cl * 4);
#pragma unroll
    for (int i = 0; i < 4; ++i) res[i] = fmaxf(res[i], pv[i]) + xv[i];
    *(float4v*)(out + (size_t)node * CH + cl * 4) = res;
  }
}

// ---------------------------------------------------------------------------
extern "C" void kernel_launch(void* const* d_in, const int* in_sizes, int n_in,
                              void* d_out, int out_size, void* d_ws, size_t ws_size,
                              hipStream_t stream) {
  const float* x    = (const float*)d_in[0];
  const float* pos  = (const float*)d_in[1];
  const float* Wv   = (const float*)d_in[2];
  const float* Wq   = (const float*)d_in[3];
  const float* Wk   = (const float*)d_in[4];
  const float* Wp   = (const float*)d_in[5];
  const float* bp   = (const float*)d_in[6];
  const int*   ei   = (const int*)d_in[7];
  float* out = (float*)d_out;

  char* wsb = (char*)d_ws;
  ushort* qbf   = (ushort*)wsb;
  unsigned int* kvp = (unsigned int*)(wsb + QBF_BYTES);
  float*  poolP = (float*)(wsb + QBF_BYTES + KVP_BYTES);

  // 1) fused pool partials + QKV projections (single dispatch)
  {
    dim3 grid(POOLBLKS + NTILES);
    dim3 block(64, 6);
    hipLaunchKernelGGL(fused_pool_qkv, grid, block, 0, stream,
                       x, Wv, Wq, Wk, qbf, kvp, poolP);
  }
  // 2) fused attention + combine (exact round-0 version)
  {
    dim3 grid(8 * ((ATILES + 7) / 8));
    dim3 block(64, 6);
    hipLaunchKernelGGL(attn_kernel, grid, block, 0, stream,
                       x, pos, Wp, bp, ei, qbf, kvp, poolP, out);
  }
}